// Round 1
// baseline (764.206 us; speedup 1.0000x reference)
//
#include <hip/hip_runtime.h>

#define Bn 8
#define Hn 640
#define Wn 640
#define CELLS (Hn*Wn)        // 409600
#define NBIN 4096
#define CAP 8192
#define KTGT 7680u
#define MAXD 128

// ws layout (u32 units): hist[Bn*NBIN] @0, cnt[Bn] @Bn*NBIN, cut[Bn] @Bn*NBIN+Bn
#define WS_ZERO_U32 (Bn*NBIN + 2*Bn)          // 32784 u32 to zero
#define WS_KEYS_BYTE (4*(Bn*NBIN + 2*Bn))     // 131136, 8B-aligned

__global__ void k_zero(unsigned* ws) {
    int p = blockIdx.x * 256 + threadIdx.x;
    if (p < WS_ZERO_U32) ws[p] = 0u;
}

__global__ void k_hist(const float2* __restrict__ cls2, unsigned* __restrict__ hist) {
    __shared__ unsigned h[NBIN];
    int b = blockIdx.y;
    for (int p = threadIdx.x; p < NBIN; p += 256) h[p] = 0u;
    __syncthreads();
    int base = b * CELLS + blockIdx.x * 2048;
    for (int k = 0; k < 8; ++k) {
        float s = cls2[base + k * 256 + threadIdx.x].y;
        if (s >= 0.6f) {
            int bin = (int)((s - 0.6f) * 10240.0f);
            bin = min(max(bin, 0), NBIN - 1);
            atomicAdd(&h[bin], 1u);
        }
    }
    __syncthreads();
    for (int p = threadIdx.x; p < NBIN; p += 256)
        if (h[p]) atomicAdd(&hist[b * NBIN + p], h[p]);
}

__global__ void k_cut(const unsigned* __restrict__ hist, float* __restrict__ cut) {
    __shared__ unsigned h[NBIN];
    __shared__ int best;
    int b = blockIdx.x, tid = threadIdx.x;
    for (int p = tid; p < NBIN; p += 256) h[p] = hist[b * NBIN + p];
    if (tid == 0) best = 0;
    __syncthreads();
    // Hillis-Steele suffix sums: h[p] = sum_{x>=p} hist[x]
    for (int off = 1; off < NBIN; off <<= 1) {
        unsigned v[16];
        for (int q = 0; q < 16; ++q) {
            int p = q * 256 + tid;
            v[q] = h[p] + ((p + off < NBIN) ? h[p + off] : 0u);
        }
        __syncthreads();
        for (int q = 0; q < 16; ++q) h[q * 256 + tid] = v[q];
        __syncthreads();
    }
    for (int q = 0; q < 16; ++q) {
        int p = q * 256 + tid;
        if (h[p] >= KTGT && (p == NBIN - 1 || h[p + 1] < KTGT)) atomicMax(&best, p);
    }
    __syncthreads();
    if (tid == 0) cut[b] = 0.6f + (float)best * (0.4f / (float)NBIN);
}

__global__ void k_compact(const float2* __restrict__ cls2, const float* __restrict__ cut,
                          unsigned* __restrict__ cnt, unsigned long long* __restrict__ keys) {
    int b = blockIdx.y;
    float c = cut[b];
    int tid = threadIdx.x, lane = tid & 63;
    int base = b * CELLS + blockIdx.x * 2048;
    for (int k = 0; k < 8; ++k) {
        int m = base + k * 256 + tid;
        float s = cls2[m].y;
        bool pred = (s >= c) && (s >= 0.6f);
        unsigned long long mask = __ballot(pred);
        if (mask) {
            int leader = __ffsll((unsigned long long)mask) - 1;
            int prefix = __popcll(mask & ((1ULL << lane) - 1ULL));
            unsigned basep = 0;
            if (lane == leader) basep = atomicAdd(&cnt[b], (unsigned)__popcll(mask));
            basep = __shfl(basep, leader);
            if (pred) {
                unsigned slot = basep + (unsigned)prefix;
                if (slot < CAP) {
                    int mm = m - b * CELLS;          // j*W + i (memory order)
                    int i = mm % Wn, j = mm / Wn;
                    unsigned n = (unsigned)(i * Hn + j);   // reference flatten order
                    keys[b * CAP + slot] =
                        ((unsigned long long)__float_as_uint(s) << 32) |
                        (unsigned long long)(~n);
                }
            }
        }
    }
}

__device__ __forceinline__ void make_box(int n, float sc, float WR, float HR,
                                         const float4* __restrict__ roi4b,
                                         float& fx1, float& fy1, float& fx2, float& fy2,
                                         float& area) {
    const float stride = (float)(1279.0 / 639.0);
    int i = n / Hn, j = n % Hn;
    float fi = (float)i, fj = (float)j;
    float b1x = truncf((stride * fi) * sc);
    float b1y = truncf((stride * fj) * sc);
    float b2x = truncf((stride * fi + 11.0f) * sc);
    float b2y = truncf((stride * fj + 11.0f) * sc);
    float4 off = roi4b[j * Wn + i];
    float x1 = b1x + (off.x * 12.0f) * sc;
    float y1 = b1y + (off.y * 12.0f) * sc;
    float x2 = b2x + (off.z * 12.0f) * sc;
    float y2 = b2y + (off.w * 12.0f) * sc;
    float w = x2 - x1, h = y2 - y1;
    float l = fmaxf(w, h);
    float nx1 = x1 + w * 0.5f - l * 0.5f;
    float ny1 = y1 + h * 0.5f - l * 0.5f;
    float nx2 = nx1 + l, ny2 = ny1 + l;
    float cx1 = fmaxf(0.0f, nx1), cy1 = fmaxf(0.0f, ny1);
    float cx2 = fminf(WR, nx2),   cy2 = fminf(HR, ny2);
    bool inv = (cx1 > cx2) || (cy1 > cy2);
    fx1 = inv ? fminf(cx1, cx2) : cx1;
    fy1 = inv ? fminf(cy1, cy2) : cy1;
    fx2 = inv ? fmaxf(cx1, cx2) : cx2;
    fy2 = inv ? fmaxf(cy1, cy2) : cy2;
    area = (fx2 - fx1 + 1.0f) * (fy2 - fy1 + 1.0f);
}

__launch_bounds__(1024)
__global__ void k_nms(const float4* __restrict__ roi4, const float* __restrict__ scale,
                      const float* __restrict__ hraw, const float* __restrict__ wraw,
                      const unsigned* __restrict__ cnt,
                      const unsigned long long* __restrict__ keys_g,
                      float* __restrict__ out) {
    __shared__ unsigned long long ks[CAP];
    __shared__ volatile float ax1[MAXD], ay1[MAXD], ax2[MAXD], ay2[MAXD],
                              aarea[MAXD], ascore[MAXD];
    int b = blockIdx.x, tid = threadIdx.x;
    int mn = (int)min(cnt[b], (unsigned)CAP);
    for (int p = tid; p < CAP; p += 1024)
        ks[p] = (p < mn) ? keys_g[b * CAP + p] : 0ULL;
    __syncthreads();
    // bitonic sort, descending
    for (int k = 2; k <= CAP; k <<= 1) {
        for (int j = k >> 1; j > 0; j >>= 1) {
            for (int p = tid; p < CAP; p += 1024) {
                int ixj = p ^ j;
                if (ixj > p) {
                    unsigned long long a = ks[p], c = ks[ixj];
                    bool descBlk = ((p & k) == 0);
                    if (descBlk ? (a < c) : (a > c)) { ks[p] = c; ks[ixj] = a; }
                }
            }
            __syncthreads();
        }
    }
    if (tid < 64) {
        int lane = tid;
        float sc = 1.0f / scale[b];
        float WR = wraw[b], HR = hraw[b];
        const float4* roi4b = roi4 + (size_t)b * CELLS;
        int n_acc = 0, pos = 0;
        while (pos < mn && n_acc < MAXD) {
            int myp = pos + lane;
            bool has = myp < mn;
            unsigned long long key = has ? ks[myp] : 0ULL;
            float s = __uint_as_float((unsigned)(key >> 32));
            unsigned n = ~(unsigned)key;
            float fx1, fy1, fx2, fy2, area;
            make_box(has ? (int)n : 0, sc, WR, HR, roi4b, fx1, fy1, fx2, fy2, area);
            bool rejected = !has;
            for (int k2 = 0; k2 < n_acc; ++k2) {
                float vx1 = ax1[k2], vy1 = ay1[k2], vx2 = ax2[k2], vy2 = ay2[k2], va = aarea[k2];
                float iw = fminf(fx2, vx2) - fmaxf(fx1, vx1) + 1.0f;
                float ih = fminf(fy2, vy2) - fmaxf(fy1, vy1) + 1.0f;
                float inter = fmaxf(0.0f, iw) * fmaxf(0.0f, ih);
                float iou = inter / (area + va - inter);
                rejected = rejected || (iou > 0.3f);
            }
            unsigned long long active = __ballot(!rejected);
            while (active && n_acc < MAXD) {
                int f = __ffsll(active) - 1;
                float bx1 = __shfl(fx1, f), by1 = __shfl(fy1, f);
                float bx2 = __shfl(fx2, f), by2 = __shfl(fy2, f);
                float bar = __shfl(area, f), bs = __shfl(s, f);
                if (lane == 0) {
                    ax1[n_acc] = bx1; ay1[n_acc] = by1; ax2[n_acc] = bx2; ay2[n_acc] = by2;
                    aarea[n_acc] = bar; ascore[n_acc] = bs;
                }
                n_acc++;
                if (lane == f) rejected = true;
                if (lane > f && !rejected) {
                    float iw = fminf(fx2, bx2) - fmaxf(fx1, bx1) + 1.0f;
                    float ih = fminf(fy2, by2) - fmaxf(fy1, by1) + 1.0f;
                    float inter = fmaxf(0.0f, iw) * fmaxf(0.0f, ih);
                    float iou = inter / (area + bar - inter);
                    if (iou > 0.3f) rejected = true;
                }
                active = __ballot(!rejected);
            }
            pos += 64;
        }
        for (int q = lane; q < MAXD * 5; q += 64) {
            int k2 = q / 5, c = q % 5;
            float v = 0.0f;
            if (k2 < n_acc) {
                v = (c == 0) ? ax1[k2] : (c == 1) ? ay1[k2] : (c == 2) ? ax2[k2]
                    : (c == 3) ? ay2[k2] : ascore[k2];
            }
            out[(b * MAXD + k2) * 5 + c] = v;
        }
    }
}

extern "C" void kernel_launch(void* const* d_in, const int* in_sizes, int n_in,
                              void* d_out, int out_size, void* d_ws, size_t ws_size,
                              hipStream_t stream) {
    const float2* cls2 = (const float2*)d_in[0];
    const float4* roi4 = (const float4*)d_in[1];
    const float* scale = (const float*)d_in[2];
    const float* hraw  = (const float*)d_in[3];
    const float* wraw  = (const float*)d_in[4];
    float* out = (float*)d_out;

    unsigned* ws   = (unsigned*)d_ws;
    unsigned* hist = ws;
    unsigned* cnt  = ws + Bn * NBIN;
    float*    cut  = (float*)(ws + Bn * NBIN + Bn);
    unsigned long long* keys = (unsigned long long*)((char*)d_ws + WS_KEYS_BYTE);

    hipLaunchKernelGGL(k_zero, dim3((WS_ZERO_U32 + 255) / 256), dim3(256), 0, stream, ws);
    hipLaunchKernelGGL(k_hist, dim3(200, Bn), dim3(256), 0, stream, cls2, hist);
    hipLaunchKernelGGL(k_cut, dim3(Bn), dim3(256), 0, stream, hist, cut);
    hipLaunchKernelGGL(k_compact, dim3(200, Bn), dim3(256), 0, stream, cls2, cut, cnt, keys);
    hipLaunchKernelGGL(k_nms, dim3(Bn), dim3(1024), 0, stream,
                       roi4, scale, hraw, wraw, cnt, keys, out);
}

// Round 2
// 314.587 us; speedup vs baseline: 2.4292x; 2.4292x over previous
//
#include <hip/hip_runtime.h>

#define Bn 8
#define Hn 640
#define Wn 640
#define CELLS (Hn*Wn)        // 409600
#define NBIN 1024
#define HB 16                // hist blocks per batch
#define CB 64                // compact blocks per batch
#define CAP 4096
#define KTGT 3584u
#define MAXD 128
#define STAGE 512            // per-block compact staging

// ws layout:
//   cnt[Bn]  u32              @ 0
//   cut[Bn]  f32              @ 32B
//   partial  u16[Bn*HB][NBIN] @ 64B    (16*1024*2*8 = 256 KB)
//   keys     u64[Bn][CAP]     @ 64B + 256KB  (256 KB)
#define WS_PART_BYTE 64
#define WS_KEYS_BYTE (64 + Bn*HB*NBIN*2)

__global__ void k_hist(const float2* __restrict__ cls2, unsigned short* __restrict__ part) {
    __shared__ unsigned h[NBIN];
    int b = blockIdx.y, blk = blockIdx.x, tid = threadIdx.x;
    for (int p = tid; p < NBIN; p += 256) h[p] = 0u;
    __syncthreads();
    int base = b * CELLS + blk * (CELLS / HB);
    for (int k = 0; k < CELLS / HB / 256; ++k) {
        float s = cls2[base + k * 256 + tid].y;
        if (s >= 0.6f) {
            int bin = (int)((s - 0.6f) * 2560.0f);   // NBIN/0.4
            bin = min(max(bin, 0), NBIN - 1);
            atomicAdd(&h[bin], 1u);
        }
    }
    __syncthreads();
    unsigned short* dst = part + (size_t)(b * HB + blk) * NBIN;
    for (int p = tid; p < NBIN; p += 256) dst[p] = (unsigned short)h[p];
}

__global__ void k_cut(const unsigned short* __restrict__ part, float* __restrict__ cut,
                      unsigned* __restrict__ cnt) {
    __shared__ unsigned h[NBIN];
    __shared__ int best;
    int b = blockIdx.x, tid = threadIdx.x;
    unsigned acc[NBIN / 256];
    for (int q = 0; q < NBIN / 256; ++q) acc[q] = 0u;
    for (int blk = 0; blk < HB; ++blk) {
        const unsigned short* src = part + (size_t)(b * HB + blk) * NBIN;
        for (int q = 0; q < NBIN / 256; ++q) acc[q] += src[q * 256 + tid];
    }
    for (int q = 0; q < NBIN / 256; ++q) h[q * 256 + tid] = acc[q];
    if (tid == 0) { best = 0; cnt[b] = 0u; }
    __syncthreads();
    // suffix sums: h[p] = count(score-bin >= p)
    for (int off = 1; off < NBIN; off <<= 1) {
        unsigned v[NBIN / 256];
        for (int q = 0; q < NBIN / 256; ++q) {
            int p = q * 256 + tid;
            v[q] = h[p] + ((p + off < NBIN) ? h[p + off] : 0u);
        }
        __syncthreads();
        for (int q = 0; q < NBIN / 256; ++q) h[q * 256 + tid] = v[q];
        __syncthreads();
    }
    for (int q = 0; q < NBIN / 256; ++q) {
        int p = q * 256 + tid;
        if (h[p] >= KTGT && (p == NBIN - 1 || h[p + 1] < KTGT)) best = p;  // unique p
    }
    __syncthreads();
    if (tid == 0) cut[b] = 0.6f + (float)best * (0.4f / (float)NBIN);
}

__global__ void k_compact(const float2* __restrict__ cls2, const float* __restrict__ cut,
                          unsigned* __restrict__ cnt, unsigned long long* __restrict__ keys) {
    __shared__ unsigned long long buf[STAGE];
    __shared__ unsigned lcnt, gbase;
    int b = blockIdx.y, blk = blockIdx.x, tid = threadIdx.x;
    float c = cut[b];
    if (tid == 0) lcnt = 0u;
    __syncthreads();
    int base = b * CELLS + blk * (CELLS / CB);
    for (int k = 0; k < CELLS / CB / 256; ++k) {
        int m = base + k * 256 + tid;
        float s = cls2[m].y;
        if (s >= c) {
            unsigned idx = atomicAdd(&lcnt, 1u);
            if (idx < STAGE) {
                int mm = m - b * CELLS;                 // j*W + i (memory order)
                int i = mm % Wn, j = mm / Wn;
                unsigned n = (unsigned)(i * Hn + j);    // reference flatten order
                buf[idx] = ((unsigned long long)__float_as_uint(s) << 32) |
                           (unsigned long long)(~n);
            }
        }
    }
    __syncthreads();
    unsigned total = min(lcnt, (unsigned)STAGE);
    if (tid == 0) gbase = atomicAdd(&cnt[b], total);
    __syncthreads();
    unsigned gb = gbase;
    for (unsigned i = tid; i < total; i += 256) {
        unsigned slot = gb + i;
        if (slot < CAP) keys[(size_t)b * CAP + slot] = buf[i];
    }
}

__device__ __forceinline__ void make_box(int n, float sc, float WR, float HR,
                                         const float4* __restrict__ roi4b,
                                         float& fx1, float& fy1, float& fx2, float& fy2,
                                         float& area) {
    const float stride = (float)(1279.0 / 639.0);
    int i = n / Hn, j = n % Hn;
    float fi = (float)i, fj = (float)j;
    float b1x = truncf((stride * fi) * sc);
    float b1y = truncf((stride * fj) * sc);
    float b2x = truncf((stride * fi + 11.0f) * sc);
    float b2y = truncf((stride * fj + 11.0f) * sc);
    float4 off = roi4b[j * Wn + i];
    float x1 = b1x + (off.x * 12.0f) * sc;
    float y1 = b1y + (off.y * 12.0f) * sc;
    float x2 = b2x + (off.z * 12.0f) * sc;
    float y2 = b2y + (off.w * 12.0f) * sc;
    float w = x2 - x1, h = y2 - y1;
    float l = fmaxf(w, h);
    float nx1 = x1 + w * 0.5f - l * 0.5f;
    float ny1 = y1 + h * 0.5f - l * 0.5f;
    float nx2 = nx1 + l, ny2 = ny1 + l;
    float cx1 = fmaxf(0.0f, nx1), cy1 = fmaxf(0.0f, ny1);
    float cx2 = fminf(WR, nx2),   cy2 = fminf(HR, ny2);
    bool inv = (cx1 > cx2) || (cy1 > cy2);
    fx1 = inv ? fminf(cx1, cx2) : cx1;
    fy1 = inv ? fminf(cy1, cy2) : cy1;
    fx2 = inv ? fmaxf(cx1, cx2) : cx2;
    fy2 = inv ? fmaxf(cy1, cy2) : cy2;
    area = (fx2 - fx1 + 1.0f) * (fy2 - fy1 + 1.0f);
}

__launch_bounds__(1024)
__global__ void k_nms(const float4* __restrict__ roi4, const float* __restrict__ scale,
                      const float* __restrict__ hraw, const float* __restrict__ wraw,
                      const unsigned* __restrict__ cnt,
                      const unsigned long long* __restrict__ keys_g,
                      float* __restrict__ out) {
    __shared__ unsigned long long ks[CAP];
    __shared__ volatile float ax1[MAXD], ay1[MAXD], ax2[MAXD], ay2[MAXD],
                              aarea[MAXD], ascore[MAXD];
    int b = blockIdx.x, tid = threadIdx.x;
    int mn = (int)min(cnt[b], (unsigned)CAP);
    for (int p = tid; p < CAP; p += 1024)
        ks[p] = (p < mn) ? keys_g[(size_t)b * CAP + p] : 0ULL;
    __syncthreads();
    // bitonic sort, descending
    for (int k = 2; k <= CAP; k <<= 1) {
        for (int j = k >> 1; j > 0; j >>= 1) {
            for (int p = tid; p < CAP; p += 1024) {
                int ixj = p ^ j;
                if (ixj > p) {
                    unsigned long long a = ks[p], c = ks[ixj];
                    bool descBlk = ((p & k) == 0);
                    if (descBlk ? (a < c) : (a > c)) { ks[p] = c; ks[ixj] = a; }
                }
            }
            __syncthreads();
        }
    }
    if (tid < 64) {
        int lane = tid;
        float sc = 1.0f / scale[b];
        float WR = wraw[b], HR = hraw[b];
        const float4* roi4b = roi4 + (size_t)b * CELLS;
        int n_acc = 0, pos = 0;
        while (pos < mn && n_acc < MAXD) {
            int myp = pos + lane;
            bool has = myp < mn;
            unsigned long long key = has ? ks[myp] : 0ULL;
            float s = __uint_as_float((unsigned)(key >> 32));
            unsigned n = ~(unsigned)key;
            float fx1, fy1, fx2, fy2, area;
            make_box(has ? (int)n : 0, sc, WR, HR, roi4b, fx1, fy1, fx2, fy2, area);
            bool rejected = !has;
            for (int k2 = 0; k2 < n_acc; ++k2) {
                float vx1 = ax1[k2], vy1 = ay1[k2], vx2 = ax2[k2], vy2 = ay2[k2], va = aarea[k2];
                float iw = fminf(fx2, vx2) - fmaxf(fx1, vx1) + 1.0f;
                float ih = fminf(fy2, vy2) - fmaxf(fy1, vy1) + 1.0f;
                float inter = fmaxf(0.0f, iw) * fmaxf(0.0f, ih);
                float iou = inter / (area + va - inter);
                rejected = rejected || (iou > 0.3f);
            }
            unsigned long long active = __ballot(!rejected);
            while (active && n_acc < MAXD) {
                int f = __ffsll(active) - 1;
                float bx1 = __shfl(fx1, f), by1 = __shfl(fy1, f);
                float bx2 = __shfl(fx2, f), by2 = __shfl(fy2, f);
                float bar = __shfl(area, f), bs = __shfl(s, f);
                if (lane == 0) {
                    ax1[n_acc] = bx1; ay1[n_acc] = by1; ax2[n_acc] = bx2; ay2[n_acc] = by2;
                    aarea[n_acc] = bar; ascore[n_acc] = bs;
                }
                n_acc++;
                if (lane == f) rejected = true;
                if (lane > f && !rejected) {
                    float iw = fminf(fx2, bx2) - fmaxf(fx1, bx1) + 1.0f;
                    float ih = fminf(fy2, by2) - fmaxf(fy1, by1) + 1.0f;
                    float inter = fmaxf(0.0f, iw) * fmaxf(0.0f, ih);
                    float iou = inter / (area + bar - inter);
                    if (iou > 0.3f) rejected = true;
                }
                active = __ballot(!rejected);
            }
            pos += 64;
        }
        for (int q = lane; q < MAXD * 5; q += 64) {
            int k2 = q / 5, c = q % 5;
            float v = 0.0f;
            if (k2 < n_acc) {
                v = (c == 0) ? ax1[k2] : (c == 1) ? ay1[k2] : (c == 2) ? ax2[k2]
                    : (c == 3) ? ay2[k2] : ascore[k2];
            }
            out[(b * MAXD + k2) * 5 + c] = v;
        }
    }
}

extern "C" void kernel_launch(void* const* d_in, const int* in_sizes, int n_in,
                              void* d_out, int out_size, void* d_ws, size_t ws_size,
                              hipStream_t stream) {
    const float2* cls2 = (const float2*)d_in[0];
    const float4* roi4 = (const float4*)d_in[1];
    const float* scale = (const float*)d_in[2];
    const float* hraw  = (const float*)d_in[3];
    const float* wraw  = (const float*)d_in[4];
    float* out = (float*)d_out;

    unsigned* cnt = (unsigned*)d_ws;
    float*    cut = (float*)((char*)d_ws + 32);
    unsigned short* part = (unsigned short*)((char*)d_ws + WS_PART_BYTE);
    unsigned long long* keys = (unsigned long long*)((char*)d_ws + WS_KEYS_BYTE);

    hipLaunchKernelGGL(k_hist, dim3(HB, Bn), dim3(256), 0, stream, cls2, part);
    hipLaunchKernelGGL(k_cut, dim3(Bn), dim3(256), 0, stream, part, cut, cnt);
    hipLaunchKernelGGL(k_compact, dim3(CB, Bn), dim3(256), 0, stream, cls2, cut, cnt, keys);
    hipLaunchKernelGGL(k_nms, dim3(Bn), dim3(1024), 0, stream,
                       roi4, scale, hraw, wraw, cnt, keys, out);
}

// Round 4
// 252.066 us; speedup vs baseline: 3.0318x; 1.2480x over previous
//
#include <hip/hip_runtime.h>

#define Bn 8
#define Hn 640
#define Wn 640
#define CELLS (Hn*Wn)        // 409600
#define NBIN 1024
#define HB 16                // hist blocks per batch
#define CB 32                // compact blocks per batch
#define CAP 4096
#define KTGT 3584u
#define MAXD 128
#define STAGE 512            // per-block compact staging (survivors/block ~ 120)

// ws layout:
//   cnt[Bn]  u32               @ 0
//   cut[Bn]  f32               @ 32B
//   partial  u16[Bn*HB][NBIN]  @ 64B            (8*16*1024*2 = 256 KB)
//   keys     u64[Bn][CAP]      @ 64B + 256KB    (256 KB)
#define WS_PART_BYTE 64
#define WS_KEYS_BYTE (64 + Bn*HB*NBIN*2)

__global__ void k_hist(const float4* __restrict__ cls4, unsigned short* __restrict__ part) {
    __shared__ unsigned h[NBIN];
    int b = blockIdx.y, blk = blockIdx.x, tid = threadIdx.x;
    for (int p = tid; p < NBIN; p += 256) h[p] = 0u;
    __syncthreads();
    const float4* src = cls4 + ((size_t)b * CELLS + blk * (CELLS / HB)) / 2;
    for (int k = 0; k < (CELLS / HB / 2) / 256; ++k) {     // 50 iters
        float4 v = src[k * 256 + tid];
        if (v.y >= 0.6f) {
            int bin = min((int)((v.y - 0.6f) * 2560.0f), NBIN - 1);
            atomicAdd(&h[bin], 1u);
        }
        if (v.w >= 0.6f) {
            int bin = min((int)((v.w - 0.6f) * 2560.0f), NBIN - 1);
            atomicAdd(&h[bin], 1u);
        }
    }
    __syncthreads();
    unsigned short* dst = part + (size_t)(b * HB + blk) * NBIN;
    for (int p = tid; p < NBIN; p += 256) dst[p] = (unsigned short)h[p];
}

__global__ void k_cut(const unsigned short* __restrict__ part, float* __restrict__ cut,
                      unsigned* __restrict__ cnt) {
    __shared__ unsigned h[NBIN];
    __shared__ int best;
    int b = blockIdx.x, tid = threadIdx.x;
    unsigned acc[NBIN / 256];
    for (int q = 0; q < NBIN / 256; ++q) acc[q] = 0u;
    for (int blk = 0; blk < HB; ++blk) {
        const unsigned short* src = part + (size_t)(b * HB + blk) * NBIN;
        for (int q = 0; q < NBIN / 256; ++q) acc[q] += src[q * 256 + tid];
    }
    for (int q = 0; q < NBIN / 256; ++q) h[q * 256 + tid] = acc[q];
    if (tid == 0) { best = 0; cnt[b] = 0u; }
    __syncthreads();
    // suffix sums: h[p] = count(score-bin >= p)
    for (int off = 1; off < NBIN; off <<= 1) {
        unsigned v[NBIN / 256];
        for (int q = 0; q < NBIN / 256; ++q) {
            int p = q * 256 + tid;
            v[q] = h[p] + ((p + off < NBIN) ? h[p + off] : 0u);
        }
        __syncthreads();
        for (int q = 0; q < NBIN / 256; ++q) h[q * 256 + tid] = v[q];
        __syncthreads();
    }
    for (int q = 0; q < NBIN / 256; ++q) {
        int p = q * 256 + tid;
        if (h[p] >= KTGT && (p == NBIN - 1 || h[p + 1] < KTGT)) best = p;  // unique p
    }
    __syncthreads();
    if (tid == 0) cut[b] = 0.6f + (float)best * (0.4f / (float)NBIN);
}

__global__ void k_compact(const float4* __restrict__ cls4, const float* __restrict__ cut,
                          unsigned* __restrict__ cnt, unsigned long long* __restrict__ keys) {
    __shared__ unsigned long long buf[STAGE];
    __shared__ unsigned lcnt, gbase;
    int b = blockIdx.y, blk = blockIdx.x, tid = threadIdx.x;
    float c = cut[b];
    if (tid == 0) lcnt = 0u;
    __syncthreads();
    int cellbase = blk * (CELLS / CB);
    const float4* src = cls4 + ((size_t)b * CELLS + cellbase) / 2;
    for (int k = 0; k < (CELLS / CB / 2) / 256; ++k) {     // 25 iters
        float4 v = src[k * 256 + tid];
        int mm = cellbase + (k * 256 + tid) * 2;
        #pragma unroll
        for (int c2 = 0; c2 < 2; ++c2) {
            float s = c2 ? v.w : v.y;
            if (s >= c) {
                unsigned idx = atomicAdd(&lcnt, 1u);
                if (idx < STAGE) {
                    int m2 = mm + c2;                      // j*W + i (memory order)
                    int i = m2 % Wn, j = m2 / Wn;
                    unsigned n = (unsigned)(i * Hn + j);   // reference flatten order
                    buf[idx] = ((unsigned long long)__float_as_uint(s) << 32) |
                               (unsigned long long)(~n);
                }
            }
        }
    }
    __syncthreads();
    unsigned total = min(lcnt, (unsigned)STAGE);
    if (tid == 0) gbase = atomicAdd(&cnt[b], total);
    __syncthreads();
    unsigned gb = gbase;
    for (unsigned i = tid; i < total; i += 256) {
        unsigned slot = gb + i;
        if (slot < CAP) keys[(size_t)b * CAP + slot] = buf[i];
    }
}

__device__ __forceinline__ void make_box(int n, float sc, float WR, float HR,
                                         const float4* __restrict__ roi4b,
                                         float& fx1, float& fy1, float& fx2, float& fy2,
                                         float& area) {
    const float stride = (float)(1279.0 / 639.0);
    int i = n / Hn, j = n % Hn;
    float fi = (float)i, fj = (float)j;
    float b1x = truncf((stride * fi) * sc);
    float b1y = truncf((stride * fj) * sc);
    float b2x = truncf((stride * fi + 11.0f) * sc);
    float b2y = truncf((stride * fj + 11.0f) * sc);
    float4 off = roi4b[j * Wn + i];
    float x1 = b1x + (off.x * 12.0f) * sc;
    float y1 = b1y + (off.y * 12.0f) * sc;
    float x2 = b2x + (off.z * 12.0f) * sc;
    float y2 = b2y + (off.w * 12.0f) * sc;
    float w = x2 - x1, h = y2 - y1;
    float l = fmaxf(w, h);
    float nx1 = x1 + w * 0.5f - l * 0.5f;
    float ny1 = y1 + h * 0.5f - l * 0.5f;
    float nx2 = nx1 + l, ny2 = ny1 + l;
    float cx1 = fmaxf(0.0f, nx1), cy1 = fmaxf(0.0f, ny1);
    float cx2 = fminf(WR, nx2),   cy2 = fminf(HR, ny2);
    bool inv = (cx1 > cx2) || (cy1 > cy2);
    fx1 = inv ? fminf(cx1, cx2) : cx1;
    fy1 = inv ? fminf(cy1, cy2) : cy1;
    fx2 = inv ? fmaxf(cx1, cx2) : cx2;
    fy2 = inv ? fmaxf(cy1, cy2) : cy2;
    area = (fx2 - fx1 + 1.0f) * (fy2 - fy1 + 1.0f);
}

__launch_bounds__(1024)
__global__ void k_nms(const float4* __restrict__ roi4, const float* __restrict__ scale,
                      const float* __restrict__ hraw, const float* __restrict__ wraw,
                      const unsigned* __restrict__ cnt,
                      const unsigned long long* __restrict__ keys_g,
                      float* __restrict__ out) {
    __shared__ unsigned long long ks[CAP];
    __shared__ float4 abox[MAXD];          // accepted x1,y1,x2,y2
    __shared__ float aarea[MAXD], ascore[MAXD];
    int b = blockIdx.x, tid = threadIdx.x;
    int mn = (int)min(cnt[b], (unsigned)CAP);
    for (int p = tid; p < CAP; p += 1024)
        ks[p] = (p < mn) ? keys_g[(size_t)b * CAP + p] : 0ULL;
    __syncthreads();
    // bitonic sort, descending, 4 elements/thread
    for (int k = 2; k <= CAP; k <<= 1) {
        for (int j = k >> 1; j > 0; j >>= 1) {
            for (int p = tid; p < CAP; p += 1024) {
                int ixj = p ^ j;
                if (ixj > p) {
                    unsigned long long a = ks[p], c = ks[ixj];
                    bool descBlk = ((p & k) == 0);
                    if (descBlk ? (a < c) : (a > c)) { ks[p] = c; ks[ixj] = a; }
                }
            }
            __syncthreads();
        }
    }
    if (tid < 64) {
        int lane = tid;
        float sc = 1.0f / scale[b];
        float WR = wraw[b], HR = hraw[b];
        const float4* roi4b = roi4 + (size_t)b * CELLS;
        int n_acc = 0, pos = 0;
        while (pos < mn && n_acc < MAXD) {
            int myp = pos + lane;
            bool has = myp < mn;
            unsigned long long key = has ? ks[myp] : 0ULL;
            float s = __uint_as_float((unsigned)(key >> 32));
            unsigned n = ~(unsigned)key;
            float fx1, fy1, fx2, fy2, area;
            make_box(has ? (int)n : 0, sc, WR, HR, roi4b, fx1, fy1, fx2, fy2, area);
            bool rejected = !has;
            // batched (pipelineable) check against all accepted so far
            for (int k2 = 0; k2 < n_acc; ++k2) {
                float4 bb = abox[k2];
                float va = aarea[k2];
                float iw = fminf(fx2, bb.z) - fmaxf(fx1, bb.x) + 1.0f;
                float ih = fminf(fy2, bb.w) - fmaxf(fy1, bb.y) + 1.0f;
                float inter = fmaxf(0.0f, iw) * fmaxf(0.0f, ih);
                float iou = inter / (area + va - inter);
                rejected |= (iou > 0.3f);
            }
            unsigned long long active = __ballot(!rejected);
            while (active && n_acc < MAXD) {
                int f = __ffsll(active) - 1;
                float bx1 = __shfl(fx1, f), by1 = __shfl(fy1, f);
                float bx2 = __shfl(fx2, f), by2 = __shfl(fy2, f);
                float bar = __shfl(area, f), bs = __shfl(s, f);
                if (lane == 0) {
                    abox[n_acc] = make_float4(bx1, by1, bx2, by2);
                    aarea[n_acc] = bar;
                    ascore[n_acc] = bs;
                }
                if (lane == f) rejected = true;        // don't self-check
                if (!rejected) {                       // surviving lanes re-check vs new box
                    float iw = fminf(fx2, bx2) - fmaxf(fx1, bx1) + 1.0f;
                    float ih = fminf(fy2, by2) - fmaxf(fy1, by1) + 1.0f;
                    float inter = fmaxf(0.0f, iw) * fmaxf(0.0f, ih);
                    float iou = inter / (area + bar - inter);
                    rejected |= (iou > 0.3f);
                }
                n_acc++;
                active = __ballot(!rejected);
            }
            pos += 64;
        }
        for (int q = lane; q < MAXD * 5; q += 64) {
            int k2 = q / 5, c = q % 5;
            float v = 0.0f;
            if (k2 < n_acc) {
                float4 bb = abox[k2];
                v = (c == 0) ? bb.x : (c == 1) ? bb.y : (c == 2) ? bb.z
                    : (c == 3) ? bb.w : ascore[k2];
            }
            out[(b * MAXD + k2) * 5 + c] = v;
        }
    }
}

extern "C" void kernel_launch(void* const* d_in, const int* in_sizes, int n_in,
                              void* d_out, int out_size, void* d_ws, size_t ws_size,
                              hipStream_t stream) {
    const float4* cls4 = (const float4*)d_in[0];
    const float4* roi4 = (const float4*)d_in[1];
    const float* scale = (const float*)d_in[2];
    const float* hraw  = (const float*)d_in[3];
    const float* wraw  = (const float*)d_in[4];
    float* out = (float*)d_out;

    unsigned* cnt = (unsigned*)d_ws;
    float*    cut = (float*)((char*)d_ws + 32);
    unsigned short* part = (unsigned short*)((char*)d_ws + WS_PART_BYTE);
    unsigned long long* keys = (unsigned long long*)((char*)d_ws + WS_KEYS_BYTE);

    hipLaunchKernelGGL(k_hist, dim3(HB, Bn), dim3(256), 0, stream, cls4, part);
    hipLaunchKernelGGL(k_cut, dim3(Bn), dim3(256), 0, stream, part, cut, cnt);
    hipLaunchKernelGGL(k_compact, dim3(CB, Bn), dim3(256), 0, stream, cls4, cut, cnt, keys);
    hipLaunchKernelGGL(k_nms, dim3(Bn), dim3(1024), 0, stream,
                       roi4, scale, hraw, wraw, cnt, keys, out);
}

// Round 5
// 236.822 us; speedup vs baseline: 3.2269x; 1.0644x over previous
//
#include <hip/hip_runtime.h>

#define Bn 8
#define Hn 640
#define Wn 640
#define CELLS (Hn*Wn)        // 409600
#define NBIN 1024
#define HB 16                // hist blocks per batch
#define CB 32                // compact blocks per batch
#define CAP 4096
#define KTGT 3584u
#define MAXD 128
#define STAGE 512            // per-block compact staging (survivors/block ~ 120)

// ws layout:
//   cnt[Bn]  u32               @ 0
//   cut[Bn]  f32               @ 32B
//   partial  u16[Bn*HB][NBIN]  @ 64B            (8*16*1024*2 = 256 KB)
//   keys     u64[Bn][CAP]      @ 64B + 256KB    (256 KB)
#define WS_PART_BYTE 64
#define WS_KEYS_BYTE (64 + Bn*HB*NBIN*2)

__global__ void k_hist(const float4* __restrict__ cls4, unsigned short* __restrict__ part) {
    __shared__ unsigned h[NBIN];
    int b = blockIdx.y, blk = blockIdx.x, tid = threadIdx.x;
    for (int p = tid; p < NBIN; p += 256) h[p] = 0u;
    __syncthreads();
    const float4* src = cls4 + ((size_t)b * CELLS + blk * (CELLS / HB)) / 2;
    for (int k = 0; k < (CELLS / HB / 2) / 256; ++k) {     // 50 iters
        float4 v = src[k * 256 + tid];
        if (v.y >= 0.6f) {
            int bin = min((int)((v.y - 0.6f) * 2560.0f), NBIN - 1);
            atomicAdd(&h[bin], 1u);
        }
        if (v.w >= 0.6f) {
            int bin = min((int)((v.w - 0.6f) * 2560.0f), NBIN - 1);
            atomicAdd(&h[bin], 1u);
        }
    }
    __syncthreads();
    unsigned short* dst = part + (size_t)(b * HB + blk) * NBIN;
    for (int p = tid; p < NBIN; p += 256) dst[p] = (unsigned short)h[p];
}

__global__ void k_cut(const unsigned short* __restrict__ part, float* __restrict__ cut,
                      unsigned* __restrict__ cnt) {
    __shared__ unsigned h[NBIN];
    __shared__ int best;
    int b = blockIdx.x, tid = threadIdx.x;
    unsigned acc[NBIN / 256];
    for (int q = 0; q < NBIN / 256; ++q) acc[q] = 0u;
    for (int blk = 0; blk < HB; ++blk) {
        const unsigned short* src = part + (size_t)(b * HB + blk) * NBIN;
        for (int q = 0; q < NBIN / 256; ++q) acc[q] += src[q * 256 + tid];
    }
    for (int q = 0; q < NBIN / 256; ++q) h[q * 256 + tid] = acc[q];
    if (tid == 0) { best = 0; cnt[b] = 0u; }
    __syncthreads();
    // suffix sums: h[p] = count(score-bin >= p)
    for (int off = 1; off < NBIN; off <<= 1) {
        unsigned v[NBIN / 256];
        for (int q = 0; q < NBIN / 256; ++q) {
            int p = q * 256 + tid;
            v[q] = h[p] + ((p + off < NBIN) ? h[p + off] : 0u);
        }
        __syncthreads();
        for (int q = 0; q < NBIN / 256; ++q) h[q * 256 + tid] = v[q];
        __syncthreads();
    }
    for (int q = 0; q < NBIN / 256; ++q) {
        int p = q * 256 + tid;
        if (h[p] >= KTGT && (p == NBIN - 1 || h[p + 1] < KTGT)) best = p;  // unique p
    }
    __syncthreads();
    if (tid == 0) cut[b] = 0.6f + (float)best * (0.4f / (float)NBIN);
}

__global__ void k_compact(const float4* __restrict__ cls4, const float* __restrict__ cut,
                          unsigned* __restrict__ cnt, unsigned long long* __restrict__ keys) {
    __shared__ unsigned long long buf[STAGE];
    __shared__ unsigned lcnt, gbase;
    int b = blockIdx.y, blk = blockIdx.x, tid = threadIdx.x;
    float c = cut[b];
    if (tid == 0) lcnt = 0u;
    __syncthreads();
    int cellbase = blk * (CELLS / CB);
    const float4* src = cls4 + ((size_t)b * CELLS + cellbase) / 2;
    for (int k = 0; k < (CELLS / CB / 2) / 256; ++k) {     // 25 iters
        float4 v = src[k * 256 + tid];
        int mm = cellbase + (k * 256 + tid) * 2;
        #pragma unroll
        for (int c2 = 0; c2 < 2; ++c2) {
            float s = c2 ? v.w : v.y;
            if (s >= c) {
                unsigned idx = atomicAdd(&lcnt, 1u);
                if (idx < STAGE) {
                    int m2 = mm + c2;                      // j*W + i (memory order)
                    int i = m2 % Wn, j = m2 / Wn;
                    unsigned n = (unsigned)(i * Hn + j);   // reference flatten order
                    buf[idx] = ((unsigned long long)__float_as_uint(s) << 32) |
                               (unsigned long long)(~n);
                }
            }
        }
    }
    __syncthreads();
    unsigned total = min(lcnt, (unsigned)STAGE);
    if (tid == 0) gbase = atomicAdd(&cnt[b], total);
    __syncthreads();
    unsigned gb = gbase;
    for (unsigned i = tid; i < total; i += 256) {
        unsigned slot = gb + i;
        if (slot < CAP) keys[(size_t)b * CAP + slot] = buf[i];
    }
}

__device__ __forceinline__ void make_box(int n, float sc, float WR, float HR,
                                         const float4* __restrict__ roi4b,
                                         float& fx1, float& fy1, float& fx2, float& fy2,
                                         float& area) {
    const float stride = (float)(1279.0 / 639.0);
    int i = n / Hn, j = n % Hn;
    float fi = (float)i, fj = (float)j;
    float b1x = truncf((stride * fi) * sc);
    float b1y = truncf((stride * fj) * sc);
    float b2x = truncf((stride * fi + 11.0f) * sc);
    float b2y = truncf((stride * fj + 11.0f) * sc);
    float4 off = roi4b[j * Wn + i];
    float x1 = b1x + (off.x * 12.0f) * sc;
    float y1 = b1y + (off.y * 12.0f) * sc;
    float x2 = b2x + (off.z * 12.0f) * sc;
    float y2 = b2y + (off.w * 12.0f) * sc;
    float w = x2 - x1, h = y2 - y1;
    float l = fmaxf(w, h);
    float nx1 = x1 + w * 0.5f - l * 0.5f;
    float ny1 = y1 + h * 0.5f - l * 0.5f;
    float nx2 = nx1 + l, ny2 = ny1 + l;
    float cx1 = fmaxf(0.0f, nx1), cy1 = fmaxf(0.0f, ny1);
    float cx2 = fminf(WR, nx2),   cy2 = fminf(HR, ny2);
    bool inv = (cx1 > cx2) || (cy1 > cy2);
    fx1 = inv ? fminf(cx1, cx2) : cx1;
    fy1 = inv ? fminf(cy1, cy2) : cy1;
    fx2 = inv ? fmaxf(cx1, cx2) : cx2;
    fy2 = inv ? fmaxf(cy1, cy2) : cy2;
    area = (fx2 - fx1 + 1.0f) * (fy2 - fy1 + 1.0f);
}

// Wave-local bitonic phases: all pairs for j<256 stay inside this wave's
// 256-element chunk. DS ops from one wave complete in order, so no block
// barrier is needed between phases — just a fence so the compiler keeps
// LDS accesses ordered and drained.
__device__ __forceinline__ void wave_phases(unsigned long long* ks, int chunkbase,
                                            int k, int jstart) {
    int lane = threadIdx.x & 63;
    for (int j = jstart; j > 0; j >>= 1) {
        #pragma unroll
        for (int e0 = 0; e0 < 256; e0 += 64) {
            int p = chunkbase + e0 + lane;
            int ixj = p ^ j;
            if (ixj > p) {
                unsigned long long a = ks[p], c = ks[ixj];
                bool descBlk = ((p & k) == 0);
                if (descBlk ? (a < c) : (a > c)) { ks[p] = c; ks[ixj] = a; }
            }
        }
        asm volatile("s_waitcnt lgkmcnt(0)" ::: "memory");
    }
}

__launch_bounds__(1024)
__global__ void k_nms(const float4* __restrict__ roi4, const float* __restrict__ scale,
                      const float* __restrict__ hraw, const float* __restrict__ wraw,
                      const unsigned* __restrict__ cnt,
                      const unsigned long long* __restrict__ keys_g,
                      float* __restrict__ out) {
    __shared__ unsigned long long ks[CAP];
    __shared__ float4 abox[MAXD];          // accepted x1,y1,x2,y2
    __shared__ float aarea[MAXD], ascore[MAXD];
    int b = blockIdx.x, tid = threadIdx.x;
    int mn = (int)min(cnt[b], (unsigned)CAP);
    for (int p = tid; p < CAP; p += 1024)
        ks[p] = (p < mn) ? keys_g[(size_t)b * CAP + p] : 0ULL;
    __syncthreads();

    int wave = tid >> 6;
    int chunkbase = wave * 256;            // 16 waves x 256 = CAP

    // k = 2..256: every phase is wave-local — zero block barriers
    for (int k = 2; k <= 256; k <<= 1)
        wave_phases(ks, chunkbase, k, k >> 1);
    __syncthreads();

    // k = 512..CAP: j>=256 phases are cross-chunk (block-wide), j<=128 wave-local
    for (int k = 512; k <= CAP; k <<= 1) {
        for (int j = k >> 1; j >= 256; j >>= 1) {
            for (int p = tid; p < CAP; p += 1024) {
                int ixj = p ^ j;
                if (ixj > p) {
                    unsigned long long a = ks[p], c = ks[ixj];
                    bool descBlk = ((p & k) == 0);
                    if (descBlk ? (a < c) : (a > c)) { ks[p] = c; ks[ixj] = a; }
                }
            }
            __syncthreads();
        }
        wave_phases(ks, chunkbase, k, 128);
        __syncthreads();
    }

    if (tid < 64) {
        int lane = tid;
        float sc = 1.0f / scale[b];
        float WR = wraw[b], HR = hraw[b];
        const float4* roi4b = roi4 + (size_t)b * CELLS;
        int n_acc = 0, pos = 0;
        while (pos < mn && n_acc < MAXD) {
            int myp = pos + lane;
            bool has = myp < mn;
            unsigned long long key = has ? ks[myp] : 0ULL;
            float s = __uint_as_float((unsigned)(key >> 32));
            unsigned n = ~(unsigned)key;
            float fx1, fy1, fx2, fy2, area;
            make_box(has ? (int)n : 0, sc, WR, HR, roi4b, fx1, fy1, fx2, fy2, area);
            bool rejected = !has;
            // batched (pipelineable) check against all accepted so far
            for (int k2 = 0; k2 < n_acc; ++k2) {
                float4 bb = abox[k2];
                float va = aarea[k2];
                float iw = fminf(fx2, bb.z) - fmaxf(fx1, bb.x) + 1.0f;
                float ih = fminf(fy2, bb.w) - fmaxf(fy1, bb.y) + 1.0f;
                float inter = fmaxf(0.0f, iw) * fmaxf(0.0f, ih);
                float iou = inter / (area + va - inter);
                rejected |= (iou > 0.3f);
            }
            unsigned long long active = __ballot(!rejected);
            while (active && n_acc < MAXD) {
                int f = __ffsll(active) - 1;
                float bx1 = __shfl(fx1, f), by1 = __shfl(fy1, f);
                float bx2 = __shfl(fx2, f), by2 = __shfl(fy2, f);
                float bar = __shfl(area, f), bs = __shfl(s, f);
                if (lane == 0) {
                    abox[n_acc] = make_float4(bx1, by1, bx2, by2);
                    aarea[n_acc] = bar;
                    ascore[n_acc] = bs;
                }
                if (lane == f) rejected = true;        // don't self-check
                if (!rejected) {                       // surviving lanes re-check vs new box
                    float iw = fminf(fx2, bx2) - fmaxf(fx1, bx1) + 1.0f;
                    float ih = fminf(fy2, by2) - fmaxf(fy1, by1) + 1.0f;
                    float inter = fmaxf(0.0f, iw) * fmaxf(0.0f, ih);
                    float iou = inter / (area + bar - inter);
                    rejected |= (iou > 0.3f);
                }
                n_acc++;
                active = __ballot(!rejected);
            }
            pos += 64;
        }
        for (int q = lane; q < MAXD * 5; q += 64) {
            int k2 = q / 5, c = q % 5;
            float v = 0.0f;
            if (k2 < n_acc) {
                float4 bb = abox[k2];
                v = (c == 0) ? bb.x : (c == 1) ? bb.y : (c == 2) ? bb.z
                    : (c == 3) ? bb.w : ascore[k2];
            }
            out[(b * MAXD + k2) * 5 + c] = v;
        }
    }
}

extern "C" void kernel_launch(void* const* d_in, const int* in_sizes, int n_in,
                              void* d_out, int out_size, void* d_ws, size_t ws_size,
                              hipStream_t stream) {
    const float4* cls4 = (const float4*)d_in[0];
    const float4* roi4 = (const float4*)d_in[1];
    const float* scale = (const float*)d_in[2];
    const float* hraw  = (const float*)d_in[3];
    const float* wraw  = (const float*)d_in[4];
    float* out = (float*)d_out;

    unsigned* cnt = (unsigned*)d_ws;
    float*    cut = (float*)((char*)d_ws + 32);
    unsigned short* part = (unsigned short*)((char*)d_ws + WS_PART_BYTE);
    unsigned long long* keys = (unsigned long long*)((char*)d_ws + WS_KEYS_BYTE);

    hipLaunchKernelGGL(k_hist, dim3(HB, Bn), dim3(256), 0, stream, cls4, part);
    hipLaunchKernelGGL(k_cut, dim3(Bn), dim3(256), 0, stream, part, cut, cnt);
    hipLaunchKernelGGL(k_compact, dim3(CB, Bn), dim3(256), 0, stream, cls4, cut, cnt, keys);
    hipLaunchKernelGGL(k_nms, dim3(Bn), dim3(1024), 0, stream,
                       roi4, scale, hraw, wraw, cnt, keys, out);
}

// Round 6
// 205.821 us; speedup vs baseline: 3.7130x; 1.1506x over previous
//
#include <hip/hip_runtime.h>

#define Bn 8
#define Hn 640
#define Wn 640
#define CELLS (Hn*Wn)        // 409600
#define NBIN 2048
#define HB 16                // hist blocks per batch
#define CB 32                // compact blocks per batch
#define NT 5                 // score tiers (lazy-sorted)
#define TCAP 1024            // per-tier capacity = sort size
#define TSTEP 832u           // tier cumulative-count step (5*832 = 4160 >= proven 3584)
#define MAXD 128
#define TSTAGE 192           // per-block per-tier staging (lambda ~ 26)

// ws layout:
//   cnt  u32[Bn*8]            @ 0      (256 B)   cnt[b*8+t]
//   cutv f32[Bn*8]            @ 256    (256 B)   cutv[b*8+t], t=0..4 descending
//   part u16[Bn*HB][NBIN]     @ 512    (512 KB)
//   keys u64[Bn][NT][TCAP]    @ 512+512KB (320 KB)
#define WS_CUT_BYTE 256
#define WS_PART_BYTE 512
#define WS_KEYS_BYTE (512 + Bn*HB*NBIN*2)

__global__ void k_hist(const float4* __restrict__ cls4, unsigned short* __restrict__ part) {
    __shared__ unsigned h[NBIN];
    int b = blockIdx.y, blk = blockIdx.x, tid = threadIdx.x;
    for (int p = tid; p < NBIN; p += 256) h[p] = 0u;
    __syncthreads();
    const float4* src = cls4 + ((size_t)b * CELLS + blk * (CELLS / HB)) / 2;
    for (int k = 0; k < (CELLS / HB / 2) / 256; ++k) {     // 50 iters
        float4 v = src[k * 256 + tid];
        if (v.y >= 0.6f) {
            int bin = min((int)((v.y - 0.6f) * 5120.0f), NBIN - 1);   // NBIN/0.4
            atomicAdd(&h[bin], 1u);
        }
        if (v.w >= 0.6f) {
            int bin = min((int)((v.w - 0.6f) * 5120.0f), NBIN - 1);
            atomicAdd(&h[bin], 1u);
        }
    }
    __syncthreads();
    unsigned short* dst = part + (size_t)(b * HB + blk) * NBIN;
    for (int p = tid; p < NBIN; p += 256) dst[p] = (unsigned short)h[p];
}

__global__ void k_cut(const unsigned short* __restrict__ part, float* __restrict__ cutv,
                      unsigned* __restrict__ cnt) {
    __shared__ unsigned h[NBIN];
    __shared__ int best[NT];
    int b = blockIdx.x, tid = threadIdx.x;
    const int Q = NBIN / 256;                 // 8
    unsigned acc[Q];
    for (int q = 0; q < Q; ++q) acc[q] = 0u;
    for (int blk = 0; blk < HB; ++blk) {
        const unsigned short* src = part + (size_t)(b * HB + blk) * NBIN;
        for (int q = 0; q < Q; ++q) acc[q] += src[q * 256 + tid];
    }
    for (int q = 0; q < Q; ++q) h[q * 256 + tid] = acc[q];
    if (tid < NT) best[tid] = 0;
    if (tid < 8) cnt[b * 8 + tid] = 0u;
    __syncthreads();
    // suffix sums: h[p] = count(score-bin >= p)
    for (int off = 1; off < NBIN; off <<= 1) {
        unsigned v[Q];
        for (int q = 0; q < Q; ++q) {
            int p = q * 256 + tid;
            v[q] = h[p] + ((p + off < NBIN) ? h[p + off] : 0u);
        }
        __syncthreads();
        for (int q = 0; q < Q; ++q) h[q * 256 + tid] = v[q];
        __syncthreads();
    }
    for (int t = 0; t < NT; ++t) {
        unsigned tgt = TSTEP * (unsigned)(t + 1);
        for (int q = 0; q < Q; ++q) {
            int p = q * 256 + tid;
            if (h[p] >= tgt && (p == NBIN - 1 || h[p + 1] < tgt)) best[t] = p;  // unique p
        }
    }
    __syncthreads();
    if (tid < NT) cutv[b * 8 + tid] = 0.6f + (float)best[tid] * (0.4f / (float)NBIN);
}

__global__ void k_compact(const float4* __restrict__ cls4, const float* __restrict__ cutv_g,
                          unsigned* __restrict__ cnt, unsigned long long* __restrict__ keys) {
    __shared__ unsigned long long buf[NT][TSTAGE];
    __shared__ unsigned lcnt[NT], gbase[NT];
    int b = blockIdx.y, blk = blockIdx.x, tid = threadIdx.x;
    float c0 = cutv_g[b * 8 + 0], c1 = cutv_g[b * 8 + 1], cmid = cutv_g[b * 8 + 2],
          c3 = cutv_g[b * 8 + 3], c4 = cutv_g[b * 8 + 4];
    if (tid < NT) lcnt[tid] = 0u;
    __syncthreads();
    int cellbase = blk * (CELLS / CB);
    const float4* src = cls4 + ((size_t)b * CELLS + cellbase) / 2;
    for (int k = 0; k < (CELLS / CB / 2) / 256; ++k) {     // 25 iters
        float4 v = src[k * 256 + tid];
        int mm = cellbase + (k * 256 + tid) * 2;
        #pragma unroll
        for (int half = 0; half < 2; ++half) {
            float s = half ? v.w : v.y;
            if (s >= c4) {
                int t = (s < c0) + (s < c1) + (s < cmid) + (s < c3);
                unsigned idx = atomicAdd(&lcnt[t], 1u);
                if (idx < TSTAGE) {
                    int m2 = mm + half;                    // j*W + i (memory order)
                    int i = m2 % Wn, j = m2 / Wn;
                    unsigned n = (unsigned)(i * Hn + j);   // reference flatten order
                    buf[t][idx] = ((unsigned long long)__float_as_uint(s) << 32) |
                                  (unsigned long long)(~n);
                }
            }
        }
    }
    __syncthreads();
    if (tid < NT) gbase[tid] = atomicAdd(&cnt[b * 8 + tid], min(lcnt[tid], (unsigned)TSTAGE));
    __syncthreads();
    for (int t = 0; t < NT; ++t) {
        unsigned tot = min(lcnt[t], (unsigned)TSTAGE);
        for (unsigned i = tid; i < tot; i += 256) {
            unsigned slot = gbase[t] + i;
            if (slot < TCAP)
                keys[((size_t)b * NT + t) * TCAP + slot] = buf[t][i];
        }
    }
}

__device__ __forceinline__ void make_box(int n, float sc, float WR, float HR,
                                         const float4* __restrict__ roi4b,
                                         float& fx1, float& fy1, float& fx2, float& fy2,
                                         float& area) {
    const float stride = (float)(1279.0 / 639.0);
    int i = n / Hn, j = n % Hn;
    float fi = (float)i, fj = (float)j;
    float b1x = truncf((stride * fi) * sc);
    float b1y = truncf((stride * fj) * sc);
    float b2x = truncf((stride * fi + 11.0f) * sc);
    float b2y = truncf((stride * fj + 11.0f) * sc);
    float4 off = roi4b[j * Wn + i];
    float x1 = b1x + (off.x * 12.0f) * sc;
    float y1 = b1y + (off.y * 12.0f) * sc;
    float x2 = b2x + (off.z * 12.0f) * sc;
    float y2 = b2y + (off.w * 12.0f) * sc;
    float w = x2 - x1, h = y2 - y1;
    float l = fmaxf(w, h);
    float nx1 = x1 + w * 0.5f - l * 0.5f;
    float ny1 = y1 + h * 0.5f - l * 0.5f;
    float nx2 = nx1 + l, ny2 = ny1 + l;
    float cx1 = fmaxf(0.0f, nx1), cy1 = fmaxf(0.0f, ny1);
    float cx2 = fminf(WR, nx2),   cy2 = fminf(HR, ny2);
    bool inv = (cx1 > cx2) || (cy1 > cy2);
    fx1 = inv ? fminf(cx1, cx2) : cx1;
    fy1 = inv ? fminf(cy1, cy2) : cy1;
    fx2 = inv ? fmaxf(cx1, cx2) : cx2;
    fy2 = inv ? fmaxf(cy1, cy2) : cy2;
    area = (fx2 - fx1 + 1.0f) * (fy2 - fy1 + 1.0f);
}

// Wave-local bitonic phases on this wave's 64-element chunk (j <= 32).
// DS ops from one wave complete in order; fence keeps the compiler honest.
__device__ __forceinline__ void wave_phases64(unsigned long long* ks, int chunkbase,
                                              int k, int jstart) {
    int lane = threadIdx.x & 63;
    for (int j = jstart; j > 0; j >>= 1) {
        int p = chunkbase + lane;
        int ixj = p ^ j;
        if (ixj > p) {
            unsigned long long a = ks[p], c = ks[ixj];
            bool descBlk = ((p & k) == 0);
            if (descBlk ? (a < c) : (a > c)) { ks[p] = c; ks[ixj] = a; }
        }
        asm volatile("s_waitcnt lgkmcnt(0)" ::: "memory");
    }
}

__launch_bounds__(1024)
__global__ void k_nms(const float4* __restrict__ roi4, const float* __restrict__ scale,
                      const float* __restrict__ hraw, const float* __restrict__ wraw,
                      const unsigned* __restrict__ cnt,
                      const unsigned long long* __restrict__ keys_g,
                      float* __restrict__ out) {
    __shared__ unsigned long long ks[TCAP];
    __shared__ float4 abox[MAXD];          // accepted x1,y1,x2,y2
    __shared__ float aarea[MAXD], ascore[MAXD];
    __shared__ int sn_acc;
    int b = blockIdx.x, tid = threadIdx.x;
    int wave = tid >> 6, lane = tid & 63;
    int chunkbase = wave * 64;             // 16 waves x 64 = TCAP

    if (tid == 0) sn_acc = 0;

    // persistent wave-0 accept state
    int n_acc = 0;
    float sc = 0.f, WR = 0.f, HR = 0.f;
    const float4* roi4b = roi4;
    if (tid < 64) {
        sc = 1.0f / scale[b];
        WR = wraw[b]; HR = hraw[b];
        roi4b = roi4 + (size_t)b * CELLS;
    }

    for (int t = 0; t < NT; ++t) {
        __syncthreads();                   // publishes sn_acc (and init)
        if (sn_acc >= MAXD) break;         // uniform
        int mt = (int)min(cnt[b * 8 + t], (unsigned)TCAP);
        ks[tid] = (tid < mt) ? keys_g[((size_t)b * NT + t) * TCAP + tid] : 0ULL;
        __syncthreads();

        if (mt > 1) {
            // bitonic sort of TCAP=1024, descending (zeros pad to the end)
            for (int k = 2; k <= 64; k <<= 1)
                wave_phases64(ks, chunkbase, k, k >> 1);
            __syncthreads();
            for (int k = 128; k <= TCAP; k <<= 1) {
                for (int j = k >> 1; j >= 64; j >>= 1) {
                    int p = tid, ixj = p ^ j;
                    if (ixj > p) {
                        unsigned long long a = ks[p], c = ks[ixj];
                        bool descBlk = ((p & k) == 0);
                        if (descBlk ? (a < c) : (a > c)) { ks[p] = c; ks[ixj] = a; }
                    }
                    __syncthreads();
                }
                wave_phases64(ks, chunkbase, k, 32);
                __syncthreads();
            }
        }

        if (tid < 64 && mt > 0) {
            int pos = 0;
            while (pos < mt && n_acc < MAXD) {
                int myp = pos + lane;
                bool has = myp < mt;
                unsigned long long key = has ? ks[myp] : 0ULL;
                float s = __uint_as_float((unsigned)(key >> 32));
                unsigned n = ~(unsigned)key;
                float fx1, fy1, fx2, fy2, area;
                make_box(has ? (int)n : 0, sc, WR, HR, roi4b, fx1, fy1, fx2, fy2, area);
                bool rejected = !has;
                // batched (pipelineable) check against all accepted so far
                for (int k2 = 0; k2 < n_acc; ++k2) {
                    float4 bb = abox[k2];
                    float va = aarea[k2];
                    float iw = fminf(fx2, bb.z) - fmaxf(fx1, bb.x) + 1.0f;
                    float ih = fminf(fy2, bb.w) - fmaxf(fy1, bb.y) + 1.0f;
                    float inter = fmaxf(0.0f, iw) * fmaxf(0.0f, ih);
                    float iou = inter / (area + va - inter);
                    rejected |= (iou > 0.3f);
                }
                unsigned long long active = __ballot(!rejected);
                while (active && n_acc < MAXD) {
                    int f = __ffsll(active) - 1;
                    float bx1 = __shfl(fx1, f), by1 = __shfl(fy1, f);
                    float bx2 = __shfl(fx2, f), by2 = __shfl(fy2, f);
                    float bar = __shfl(area, f), bs = __shfl(s, f);
                    if (lane == 0) {
                        abox[n_acc] = make_float4(bx1, by1, bx2, by2);
                        aarea[n_acc] = bar;
                        ascore[n_acc] = bs;
                    }
                    if (lane == f) rejected = true;        // don't self-check
                    if (!rejected) {                       // survivors re-check vs new box
                        float iw = fminf(fx2, bx2) - fmaxf(fx1, bx1) + 1.0f;
                        float ih = fminf(fy2, by2) - fmaxf(fy1, by1) + 1.0f;
                        float inter = fmaxf(0.0f, iw) * fmaxf(0.0f, ih);
                        float iou = inter / (area + bar - inter);
                        rejected |= (iou > 0.3f);
                    }
                    n_acc++;
                    active = __ballot(!rejected);
                }
                pos += 64;
            }
            if (tid == 0) sn_acc = n_acc;
        }
    }
    __syncthreads();

    if (tid < 64) {
        for (int q = lane; q < MAXD * 5; q += 64) {
            int k2 = q / 5, c = q % 5;
            float v = 0.0f;
            if (k2 < n_acc) {
                float4 bb = abox[k2];
                v = (c == 0) ? bb.x : (c == 1) ? bb.y : (c == 2) ? bb.z
                    : (c == 3) ? bb.w : ascore[k2];
            }
            out[(b * MAXD + k2) * 5 + c] = v;
        }
    }
}

extern "C" void kernel_launch(void* const* d_in, const int* in_sizes, int n_in,
                              void* d_out, int out_size, void* d_ws, size_t ws_size,
                              hipStream_t stream) {
    const float4* cls4 = (const float4*)d_in[0];
    const float4* roi4 = (const float4*)d_in[1];
    const float* scale = (const float*)d_in[2];
    const float* hraw  = (const float*)d_in[3];
    const float* wraw  = (const float*)d_in[4];
    float* out = (float*)d_out;

    unsigned* cnt = (unsigned*)d_ws;
    float*    cutv = (float*)((char*)d_ws + WS_CUT_BYTE);
    unsigned short* part = (unsigned short*)((char*)d_ws + WS_PART_BYTE);
    unsigned long long* keys = (unsigned long long*)((char*)d_ws + WS_KEYS_BYTE);

    hipLaunchKernelGGL(k_hist, dim3(HB, Bn), dim3(256), 0, stream, cls4, part);
    hipLaunchKernelGGL(k_cut, dim3(Bn), dim3(256), 0, stream, part, cutv, cnt);
    hipLaunchKernelGGL(k_compact, dim3(CB, Bn), dim3(256), 0, stream, cls4, cutv, cnt, keys);
    hipLaunchKernelGGL(k_nms, dim3(Bn), dim3(1024), 0, stream,
                       roi4, scale, hraw, wraw, cnt, keys, out);
}